// Round 14
// baseline (172.993 us; speedup 1.0000x reference)
//
#include <hip/hip_runtime.h>
#include <stdint.h>

// Problem constants
#define S_  1024
#define M_  1024
#define B_  4
#define D_  1024
#define H_  16
#define DH_ 64
#define T_  2048

typedef __attribute__((ext_vector_type(8))) short bf8;           // 8 x bf16 (A/B frag)
typedef __attribute__((ext_vector_type(4))) float f32x4;         // C/D frag 16x16
typedef __attribute__((ext_vector_type(16))) float f32x16;       // C/D frag 32x32
typedef __attribute__((ext_vector_type(8))) unsigned short u16x8;
typedef __attribute__((ext_vector_type(4))) unsigned short u16x4;
typedef __attribute__((ext_vector_type(4))) unsigned int u32x4;
typedef unsigned short u16;

#define MFMA(a, b, c)   __builtin_amdgcn_mfma_f32_16x16x32_bf16((a), (b), (c), 0, 0, 0)
#define MFMA32(a, b, c) __builtin_amdgcn_mfma_f32_32x32x16_bf16((a), (b), (c), 0, 0, 0)

// chunk swizzle for 64B LDS rows (cbf/wqt layout pairs with qkvs reads)
#define SIG(r) ((((r) >> 1) ^ ((r) >> 3)) & 3)
#define SCALE_Q 0.1803368801f   // 0.125 * log2(e), folded into Q at store

static __device__ __forceinline__ u16 f2bf(float f) {
  unsigned int u = __builtin_bit_cast(unsigned int, f);
  u += 0x7fffu + ((u >> 16) & 1u);   // RNE
  return (u16)(u >> 16);
}

static __device__ __forceinline__ void gload16(const void* g, void* l) {
  __builtin_amdgcn_global_load_lds((const __attribute__((address_space(1))) unsigned int*)g,
                                   (__attribute__((address_space(3))) unsigned int*)l,
                                   16, 0, 0);
}

static __device__ __forceinline__ float fexp2(float x) {
  return __builtin_amdgcn_exp2f(x);
}
static __device__ __forceinline__ unsigned int cvtpk(float lo, float hi) {
  unsigned int r; asm("v_cvt_pk_bf16_f32 %0, %1, %2" : "=v"(r) : "v"(lo), "v"(hi)); return r;
}
static __device__ __forceinline__ void plswap(unsigned int& a, unsigned int& b) {
  asm volatile("s_nop 1\n\tv_permlane32_swap_b32 %0, %1" : "+v"(a), "+v"(b));
}

// ------- merged prep: bid<4096 -> c_bf16=[mem;x+pos] (SIG-swz) + xp ---------
//         bid>=4096 -> weight transpose wqkv(SIG-swz) / wo(linear)
__global__ __launch_bounds__(256) void k_prep2(const float* __restrict__ x,
    const float* __restrict__ pos, const float* __restrict__ mem,
    const float* __restrict__ wqkv, const float* __restrict__ wo,
    u16* __restrict__ cbf, float* __restrict__ xp,
    u16* __restrict__ wqt, u16* __restrict__ wot)
{
  __shared__ float tl[64][65];
  const int bid = blockIdx.x;
  const int tid = threadIdx.x;
  if (bid < 4096) {
    const int gid = bid * 256 + tid;
    const int e = gid * 8;                  // elem idx into [8192][1024]
    const int row = e >> 10, col = e & 1023;
    float4 v0, v1;
    if (e < M_ * B_ * D_) {
      v0 = *(const float4*)(mem + e);
      v1 = *(const float4*)(mem + e + 4);
    } else {
      const int i2 = e - M_ * B_ * D_;
      v0 = *(const float4*)(x + i2);
      v1 = *(const float4*)(x + i2 + 4);
      const int srow = i2 >> 12;
      const float4 p0 = *(const float4*)(pos + srow * 1024 + col);
      const float4 p1 = *(const float4*)(pos + srow * 1024 + col + 4);
      v0.x += p0.x; v0.y += p0.y; v0.z += p0.z; v0.w += p0.w;
      v1.x += p1.x; v1.y += p1.y; v1.z += p1.z; v1.w += p1.w;
      *(float4*)(xp + i2) = v0;
      *(float4*)(xp + i2 + 4) = v1;
    }
    u16x8 c;
    c[0] = f2bf(v0.x); c[1] = f2bf(v0.y); c[2] = f2bf(v0.z); c[3] = f2bf(v0.w);
    c[4] = f2bf(v1.x); c[5] = f2bf(v1.y); c[6] = f2bf(v1.z); c[7] = f2bf(v1.w);
    const int ch = col >> 3;
    const int chs = (ch & ~3) | ((ch & 3) ^ SIG(row));
    *(u16x8*)(cbf + (size_t)row * 1024 + chs * 8) = c;
    return;
  }
  // ---- weight transpose part: 1024 blocks = 16 x 64 ----
  const int wb = bid - 4096;
  const int bx = wb & 15, by = wb >> 4;
  const float* src; u16* dst; int Cc, swz, c0;
  if (by < 48) { src = wqkv; dst = wqt; Cc = 3072; swz = 1; c0 = by * 64; }
  else         { src = wo;   dst = wot; Cc = 1024; swz = 0; c0 = (by - 48) * 64; }
  const int Rr = 1024;
  const int r0 = bx * 64;
  const int lr = tid >> 4, lc = (tid & 15) * 4;
  for (int i = 0; i < 4; ++i) {
    const int rr = lr + i * 16;
    const float4 v = *(const float4*)(src + (size_t)(r0 + rr) * Cc + c0 + lc);
    tl[rr][lc] = v.x; tl[rr][lc + 1] = v.y; tl[rr][lc + 2] = v.z; tl[rr][lc + 3] = v.w;
  }
  __syncthreads();
  const int c = tid >> 2, k0 = (tid & 3) * 16;
  u16x8 a, b;
  for (int j = 0; j < 8; ++j) { a[j] = f2bf(tl[k0 + j][c]); b[j] = f2bf(tl[k0 + 8 + j][c]); }
  const int roww = c0 + c;
  int ch0 = (r0 + k0) >> 3, ch1 = ((r0 + k0) >> 3) + 1;
  if (swz) {
    const int sx = SIG(roww);
    ch0 = (ch0 & ~3) | ((ch0 & 3) ^ sx);
    ch1 = (ch1 & ~3) | ((ch1 & 3) ^ sx);
  }
  u16* dp = dst + (size_t)roww * Rr;
  *(u16x8*)(dp + ch0 * 8) = a;
  *(u16x8*)(dp + ch1 * 8) = b;
}

// ====== QKV GEMM: 128x128, 3-stage LDS, counted vmcnt (R5/R9 proven best) ===
// V-blocks: epilogue re-staged through LDS for coalesced 16B VT stores.
// Q-blocks: store Q pre-scaled by SCALE_Q (softmax scale folded in).
__global__ __launch_bounds__(256, 3) void k_gemm_qkvs(const u16* __restrict__ A,
    const u16* __restrict__ Bt, u16* __restrict__ Qd, u16* __restrict__ Kd,
    u16* __restrict__ VTd)
{
  __shared__ u16 smem[24576];                 // 48KB: 3x8KB A | 3x8KB B
  u16 (*sA)[4096] = (u16(*)[4096])smem;
  u16 (*sB)[4096] = (u16(*)[4096])(smem + 12288);
  const int tid = threadIdx.x, lane = tid & 63, wave = tid >> 6;
  const int lrow = lane & 15, lgrp = lane >> 4;
  const int wm = (wave >> 1) * 64, wn = (wave & 1) * 64;
  const int sr = lane >> 2, sk = (lane & 3) * 8;

  // 1280 live 128x128 tiles, XCD-bijective chunking (1280 = 8*160)
  const int bid = blockIdx.x;
  const int lid = (bid & 7) * 160 + (bid >> 3);
  int rowb, colb;
  if (lid < 512) { rowb = lid >> 4; colb = 8 + (lid & 15); }
  else { const int l2 = lid - 512; const int q = l2 / 24; rowb = 32 + q; colb = l2 - q * 24; }
  const int row0 = rowb * 128, col0 = colb * 128;

  f32x4 acc[4][4];
#pragma unroll
  for (int i = 0; i < 4; ++i)
#pragma unroll
    for (int j = 0; j < 4; ++j) acc[i][j] = f32x4{0.f, 0.f, 0.f, 0.f};

#define STAGE_S(bufi, kt) do { const int k0_ = (kt) * 32;                      \
    _Pragma("unroll") for (int s_ = 0; s_ < 2; ++s_) {                         \
      const int rr_ = (wave * 2 + s_) * 16 + sr;                               \
      gload16(A + (size_t)(row0 + rr_) * 1024 + k0_ + sk,                      \
              &sA[bufi][(wave * 2 + s_) * 512]);                               \
      gload16(Bt + (size_t)(col0 + rr_) * 1024 + k0_ + sk,                     \
              &sB[bufi][(wave * 2 + s_) * 512]);                               \
    } } while (0)

  // prologue: stage tiles 0 and 1 (8 loads/thread outstanding)
  STAGE_S(0, 0); STAGE_S(1, 1);

  int c0 = 0;
#pragma unroll 1
  for (int t = 0; t < 32; ++t) {
    if (t < 31) { asm volatile("s_waitcnt vmcnt(4)" ::: "memory"); }
    else        { asm volatile("s_waitcnt vmcnt(0)" ::: "memory"); }
    __builtin_amdgcn_s_barrier();
    __builtin_amdgcn_sched_barrier(0);
    const int c2 = (c0 + 2 >= 3) ? c0 - 1 : c0 + 2;
    if (t <= 29) STAGE_S(c2, t + 2);
    bf8 af[4], bfv[4];
#pragma unroll
    for (int i = 0; i < 4; ++i) {
      const int r_ = wm + i * 16 + lrow;
      af[i] = *(const bf8*)&sA[c0][r_ * 32 + ((lgrp ^ SIG(r_)) << 3)];
    }
#pragma unroll
    for (int j = 0; j < 4; ++j) {
      const int r_ = wn + j * 16 + lrow;
      bfv[j] = *(const bf8*)&sB[c0][r_ * 32 + ((lgrp ^ SIG(r_)) << 3)];
    }
    __builtin_amdgcn_s_setprio(1);
#pragma unroll
    for (int i = 0; i < 4; ++i)
#pragma unroll
      for (int j = 0; j < 4; ++j) acc[i][j] = MFMA(af[i], bfv[j], acc[i][j]);
    __builtin_amdgcn_s_setprio(0);
    c0 = (c0 == 2) ? 0 : c0 + 1;
  }

  const int which = col0 >> 10;     // block-uniform: 0=Q 1=K 2=V
  if (which == 2) {
    // ---- V epilogue via LDS re-stage: ebuf[ro 8][dh 64][tl pad 40] ----
    __syncthreads();                 // all waves done with sA/sB reads
    u16* ebuf = smem;                // 8*64*40 u16 = 40KB (fits 48KB)
#pragma unroll
    for (int i = 0; i < 4; ++i)
#pragma unroll
      for (int j = 0; j < 4; ++j)
#pragma unroll
        for (int r = 0; r < 4; ++r) {
          const int ro = r * 2 + (wn >> 6);
          const int dh = j * 16 + lrow;
          const int tl2 = (wm >> 2) + i * 4 + lgrp;
          ebuf[(ro * 64 + dh) * 40 + tl2] = f2bf(acc[i][j][r]);
        }
    __syncthreads();
    const int h0 = (col0 & 1023) >> 6;
    const int base_t = (rowb & ~1) * 32;          // 64-aligned t base
    const int off0 = (rowb & 1) * 32;             // tile offset inside 64-chunk
#pragma unroll
    for (int k = 0; k < 8; ++k) {
      const int slot = k * 256 + tid;             // 2048 slots = 512 rows x 4
      const int row = slot >> 2, l4 = slot & 3;
      const int ro = row >> 6, dh = row & 63;
      const int b = ro >> 1, hloc = ro & 1;
      const int bh = b * 16 + h0 + hloc;
      const u16x8 v = *(const u16x8*)&ebuf[row * 40 + l4 * 8];
      const int chunk = (off0 + l4 * 8) ^ ((dh & 7) << 3);
      *(u16x8*)(VTd + (size_t)(bh * 64 + dh) * T_ + base_t + chunk) = v;
    }
    return;
  }

  // epilogue (Q / K): direct stores (already line-local)
#pragma unroll
  for (int i = 0; i < 4; ++i)
#pragma unroll
    for (int j = 0; j < 4; ++j)
#pragma unroll
      for (int r = 0; r < 4; ++r) {
        const int grow = row0 + wm + i * 16 + lgrp * 4 + r;   // c-row = t*B+b
        const int gcol = col0 + wn + j * 16 + lrow;
        const int t = grow >> 2, bb2 = grow & 3;
        const int rem = gcol & 1023;
        const int bh = bb2 * 16 + (rem >> 6), dh = rem & 63;
        if (which == 0) {
          if (t >= M_)
            Qd[((size_t)bh * S_ + (t - M_)) * 64 + dh] = f2bf(acc[i][j][r] * SCALE_Q);
        } else {
          Kd[((size_t)bh * T_ + t) * 64 + (dh ^ ((t & 7) << 3))] = f2bf(acc[i][j][r]);
        }
      }
}

// ===== out-proj GEMM: 64x128 tiles, 3-stage counted vmcnt, grid 512 =========
__global__ __launch_bounds__(256) void k_gemm_out(const u16* __restrict__ A,
    const u16* __restrict__ Bt, const float* __restrict__ xp,
    float* __restrict__ y)
{
  __shared__ u16 sA[3][2048];   // [64 rows][32 k]
  __shared__ u16 sB[3][4096];   // [128 rows][32 k]
  const int tid = threadIdx.x, lane = tid & 63, wave = tid >> 6;
  const int lrow = lane & 15, lgrp = lane >> 4;
  const int wm = (wave >> 1) * 32, wn = (wave & 1) * 64;
  const int row0 = blockIdx.y * 64, col0 = blockIdx.x * 128;
  const int sr = lane >> 2, sk = (lane & 3) * 8;

  f32x4 acc[2][4];
  for (int i = 0; i < 2; ++i)
    for (int j = 0; j < 4; ++j) acc[i][j] = f32x4{0.f, 0.f, 0.f, 0.f};

#define STAGE_O(bufi, kt) do { const int k0_ = (kt) * 32;                      \
    const int rra_ = wave * 16 + sr;                                           \
    gload16(A + (size_t)(row0 + rra_) * 1024 + k0_ + sk,                       \
            &sA[bufi][wave * 512]);                                            \
    _Pragma("unroll") for (int s_ = 0; s_ < 2; ++s_) {                         \
      const int rrb_ = (wave * 2 + s_) * 16 + sr;                              \
      gload16(Bt + (size_t)(col0 + rrb_) * 1024 + k0_ + sk,                    \
              &sB[bufi][(wave * 2 + s_) * 512]);                               \
    } } while (0)

  // prologue: tiles 0,1 staged (6 loads/thread outstanding)
  STAGE_O(0, 0); STAGE_O(1, 1);

  int c0 = 0;
#pragma unroll 1
  for (int kt = 0; kt < 32; ++kt) {
    if (kt < 31) { asm volatile("s_waitcnt vmcnt(3)" ::: "memory"); }
    else         { asm volatile("s_waitcnt vmcnt(0)" ::: "memory"); }
    __builtin_amdgcn_s_barrier();
    __builtin_amdgcn_sched_barrier(0);
    const int c2 = (c0 + 2 >= 3) ? c0 - 1 : c0 + 2;
    if (kt <= 29) STAGE_O(c2, kt + 2);
    bf8 af[2], bfv[4];
    const u16* pa = &sA[c0][(wm + lrow) * 32 + lgrp * 8];
    const u16* pb = &sB[c0][(wn + lrow) * 32 + lgrp * 8];
#pragma unroll
    for (int i = 0; i < 2; ++i) af[i] = *(const bf8*)(pa + i * 512);
#pragma unroll
    for (int j = 0; j < 4; ++j) bfv[j] = *(const bf8*)(pb + j * 512);
    __builtin_amdgcn_s_setprio(1);
#pragma unroll
    for (int i = 0; i < 2; ++i)
#pragma unroll
      for (int j = 0; j < 4; ++j) acc[i][j] = MFMA(af[i], bfv[j], acc[i][j]);
    __builtin_amdgcn_s_setprio(0);
    c0 = (c0 == 2) ? 0 : c0 + 1;
  }

  for (int i = 0; i < 2; ++i)
    for (int j = 0; j < 4; ++j)
      for (int r = 0; r < 4; ++r) {
        const int grow = row0 + wm + i * 16 + lgrp * 4 + r;
        const int gcol = col0 + wn + j * 16 + lrow;
        y[(size_t)grow * 1024 + gcol] = acc[i][j][r] + xp[(size_t)grow * 1024 + gcol];
      }
}

// ---------------- flash attention, swapped-QK^T 32x32, 2-wave blocks --------
// grid 1024 = 64 bh x 16 qb (QBLK=64), 128 threads. XCD-chunked: each XCD
// owns 8 whole heads. Q pre-scaled by SCALE_Q (no per-tile scale multiply).
__global__ __launch_bounds__(128) void k_attn(const u16* __restrict__ Qd,
    const u16* __restrict__ Kd, const u16* __restrict__ VTd,
    u16* __restrict__ vec)
{
  __shared__ u16 Kl[2][4096];   // [64 t][64 dh], dh XOR-swizzled
  __shared__ u16 Vl[2][4096];   // [64 dh][64 t], t  XOR-swizzled
  const int tid = threadIdx.x, lane = tid & 63, wave = tid >> 6;
  const int ql = lane & 31, hi = lane >> 5;
  const int bid = blockIdx.x;
  const int sw = (bid & 7) * 128 + (bid >> 3);  // bijective, bh-chunked per XCD
  const int bh = sw >> 4, qb = sw & 15;
  const int bb = bh >> 4, hh = bh & 15;
  const int q0 = qb * 64 + wave * 32;
  const int myq = q0 + ql;
  const int klim = M_ + myq;

  bf8 qf[4];
  const u16* qrow = Qd + ((size_t)bh * S_ + myq) * 64 + hi * 8;
#pragma unroll
  for (int c = 0; c < 4; ++c) qf[c] = *(const bf8*)(qrow + c * 16);

  const u16* kb = Kd + (size_t)bh * T_ * 64;
  const u16* vb = VTd + (size_t)bh * 64 * T_;

  f32x16 o0, o1;
#pragma unroll
  for (int r = 0; r < 16; ++r) { o0[r] = 0.f; o1[r] = 0.f; }
  float m_run = 0.f, l_run = 0.f;

  const int nkt = (M_ + qb * 64 + 64) >> 6;   // 17 + qb

  auto stage = [&](int buf, int kt) {
    const int t0 = kt * 64;
#pragma unroll
    for (int i = 0; i < 4; ++i) {          // K tile: 512 chunks over 128 thr
      const int ch = i * 128 + tid;
      gload16(kb + (size_t)t0 * 64 + ch * 8, &Kl[buf][ch * 8]);
    }
#pragma unroll
    for (int i = 0; i < 4; ++i) {          // VT tile
      const int ch = i * 128 + tid;
      gload16(vb + (size_t)(ch >> 3) * T_ + t0 + (ch & 7) * 8, &Vl[buf][ch * 8]);
    }
  };

  stage(0, 0);
  int cur = 0;
  for (int kt = 0; kt < nkt; ++kt) {
    if (kt + 1 < nkt) {
      stage(cur ^ 1, kt + 1);
      asm volatile("s_waitcnt vmcnt(8)" ::: "memory");  // cur's 8 loads done
    } else {
      asm volatile("s_waitcnt vmcnt(0)" ::: "memory");
    }
    __builtin_amdgcn_s_barrier();

    const u16* Kc = Kl[cur];
    const u16* Vc = Vl[cur];

    f32x16 s0, s1;
#pragma unroll
    for (int r = 0; r < 16; ++r) { s0[r] = 0.f; s1[r] = 0.f; }
    const int tr0 = ql, tr1 = 32 + ql;
    const int sw0 = (tr0 & 7) << 3;
    __builtin_amdgcn_s_setprio(1);
#pragma unroll
    for (int c = 0; c < 4; ++c) {
      const int db = c * 16 + hi * 8;
      const bf8 ka = *(const bf8*)(Kc + tr0 * 64 + (db ^ sw0));
      const bf8 kbfr = *(const bf8*)(Kc + tr1 * 64 + (db ^ sw0));
      s0 = MFMA32(ka, qf[c], s0);
      s1 = MFMA32(kbfr, qf[c], s1);
    }
    __builtin_amdgcn_s_setprio(0);

    float p0[16], p1[16];
#pragma unroll
    for (int r = 0; r < 16; ++r) { p0[r] = s0[r]; p1[r] = s1[r]; }  // scale in Q
    if (kt * 64 + 63 > M_ + q0) {
#pragma unroll
      for (int r = 0; r < 16; ++r) {
        const int kg = kt * 64 + (r & 3) + 8 * (r >> 2) + 4 * hi;
        if (kg > klim)      p0[r] = -1e30f;
        if (kg + 32 > klim) p1[r] = -1e30f;
      }
    }
    float mx = fmaxf(p0[0], p1[0]);
#pragma unroll
    for (int r = 1; r < 16; ++r) mx = fmaxf(mx, fmaxf(p0[r], p1[r]));
    mx = fmaxf(mx, __shfl_xor(mx, 32));
    if (__any(mx - m_run > 8.f)) {
      const float mnew = fmaxf(m_run, mx);
      const float al = fexp2(m_run - mnew);
      l_run *= al;
#pragma unroll
      for (int r = 0; r < 16; ++r) {
        const int qloc = (r & 3) + 8 * (r >> 2) + 4 * hi;
        const float ar = __shfl(al, (lane & 32) + qloc);
        o0[r] *= ar; o1[r] *= ar;
      }
      m_run = mnew;
    }
    float rs = 0.f;
#pragma unroll
    for (int r = 0; r < 16; ++r) {
      p0[r] = fexp2(p0[r] - m_run);
      p1[r] = fexp2(p1[r] - m_run);
      rs += p0[r] + p1[r];
    }
    rs += __shfl_xor(rs, 32);
    l_run += rs;

    bf8 paf[2][2];
    {
      unsigned int a0 = cvtpk(p0[0], p0[1]),  a1 = cvtpk(p0[2], p0[3]);
      unsigned int a2 = cvtpk(p0[4], p0[5]),  a3 = cvtpk(p0[6], p0[7]);
      unsigned int b0 = cvtpk(p0[8], p0[9]),  b1 = cvtpk(p0[10], p0[11]);
      unsigned int b2 = cvtpk(p0[12], p0[13]), b3 = cvtpk(p0[14], p0[15]);
      plswap(a0, a2); plswap(a1, a3); plswap(b0, b2); plswap(b1, b3);
      u32x4 f0 = {a0, a1, a2, a3}, f1 = {b0, b1, b2, b3};
      paf[0][0] = __builtin_bit_cast(bf8, f0);
      paf[0][1] = __builtin_bit_cast(bf8, f1);
    }
    {
      unsigned int a0 = cvtpk(p1[0], p1[1]),  a1 = cvtpk(p1[2], p1[3]);
      unsigned int a2 = cvtpk(p1[4], p1[5]),  a3 = cvtpk(p1[6], p1[7]);
      unsigned int b0 = cvtpk(p1[8], p1[9]),  b1 = cvtpk(p1[10], p1[11]);
      unsigned int b2 = cvtpk(p1[12], p1[13]), b3 = cvtpk(p1[14], p1[15]);
      plswap(a0, a2); plswap(a1, a3); plswap(b0, b2); plswap(b1, b3);
      u32x4 f0 = {a0, a1, a2, a3}, f1 = {b0, b1, b2, b3};
      paf[1][0] = __builtin_bit_cast(bf8, f0);
      paf[1][1] = __builtin_bit_cast(bf8, f1);
    }

    __builtin_amdgcn_s_setprio(1);
#pragma unroll
    for (int kc = 0; kc < 4; ++kc) {
      const int tb = kc * 16 + hi * 8;
      const bf8 pfrag = paf[kc >> 1][kc & 1];
      const int vr0 = ql, vr1 = 32 + ql;
      const bf8 vf0 = *(const bf8*)(Vc + vr0 * 64 + (tb ^ ((vr0 & 7) << 3)));
      const bf8 vf1 = *(const bf8*)(Vc + vr1 * 64 + (tb ^ ((vr1 & 7) << 3)));
      o0 = MFMA32(pfrag, vf0, o0);
      o1 = MFMA32(pfrag, vf1, o1);
    }
    __builtin_amdgcn_s_setprio(0);
    __builtin_amdgcn_s_barrier();
    cur ^= 1;
  }

  const float linv = 1.0f / l_run;
#pragma unroll
  for (int r = 0; r < 16; ++r) {
    const int qloc = (r & 3) + 8 * (r >> 2) + 4 * hi;
    const float li = __shfl(linv, (lane & 32) + qloc);
    const int srow = q0 + qloc;
    const size_t base = ((size_t)srow * B_ + bb) * 1024 + hh * 64;
    vec[base + ql]      = f2bf(o0[r] * li);
    vec[base + 32 + ql] = f2bf(o1[r] * li);
  }
}

// ---------------- LayerNorm -------------------------------------------------
__global__ __launch_bounds__(256) void k_ln(const float* __restrict__ y,
    const float* __restrict__ g, const float* __restrict__ be,
    float* __restrict__ out)
{
  const int row = blockIdx.x, tid = threadIdx.x;
  const float4 v = *(const float4*)(y + (size_t)row * 1024 + tid * 4);
  float s = v.x + v.y + v.z + v.w;
  float ss = v.x * v.x + v.y * v.y + v.z * v.z + v.w * v.w;
  for (int mk = 1; mk < 64; mk <<= 1) { s += __shfl_xor(s, mk); ss += __shfl_xor(ss, mk); }
  __shared__ float red[8];
  if ((tid & 63) == 0) { red[tid >> 6] = s; red[4 + (tid >> 6)] = ss; }
  __syncthreads();
  s = red[0] + red[1] + red[2] + red[3];
  ss = red[4] + red[5] + red[6] + red[7];
  const float mu = s * (1.0f / 1024.0f);
  const float var = ss * (1.0f / 1024.0f) - mu * mu;
  const float rstd = rsqrtf(var + 1e-5f);
  const float4 gg = *(const float4*)(g + tid * 4);
  const float4 bb = *(const float4*)(be + tid * 4);
  float4 o;
  o.x = (v.x - mu) * rstd * gg.x + bb.x;
  o.y = (v.y - mu) * rstd * gg.y + bb.y;
  o.z = (v.z - mu) * rstd * gg.z + bb.z;
  o.w = (v.w - mu) * rstd * gg.w + bb.w;
  *(float4*)(out + (size_t)row * 1024 + tid * 4) = o;
}

// ---------------------------------------------------------------------------
extern "C" void kernel_launch(void* const* d_in, const int* in_sizes, int n_in,
                              void* d_out, int out_size, void* d_ws, size_t ws_size,
                              hipStream_t stream)
{
  const float* x     = (const float*)d_in[0];
  const float* pos   = (const float*)d_in[1];
  const float* mem   = (const float*)d_in[2];
  // d_in[3] = mask: purely causal (j > i+M), computed analytically in k_attn
  const float* wqkv  = (const float*)d_in[4];
  const float* wo    = (const float*)d_in[5];
  const float* gamma = (const float*)d_in[6];
  const float* beta  = (const float*)d_in[7];
  float* out = (float*)d_out;

  if (ws_size < ((size_t)104 << 20)) return;  // need 104 MB scratch

  char* ws = (char*)d_ws;
  u16*   cbf = (u16*)(ws + 0);                      // 16MB  [8192][1024] bf16 (sig-swz)
  float* y   = (float*)(ws + 0);                    // 16MB  (reuses cbf after gemm1)
  float* xp  = (float*)(ws + ((size_t)16 << 20));   // 16MB  [4096][1024] f32
  u16*   wqt = (u16*)(ws + ((size_t)32 << 20));     // 6MB   [3072][1024] bf16 (sig-swz)
  u16*   wot = (u16*)(ws + ((size_t)38 << 20));     // 2MB   [1024][1024] bf16
  u16*   Qd  = (u16*)(ws + ((size_t)40 << 20));     // 8MB   [64][1024][64] (pre-scaled)
  u16*   Kd  = (u16*)(ws + ((size_t)48 << 20));     // 16MB  [64][2048][64] (swz)
  u16*   VTd = (u16*)(ws + ((size_t)80 << 20));     // 16MB  [64][64][2048] (swz)
  u16*   vec = (u16*)(ws + ((size_t)96 << 20));     // 8MB   [4096][1024] bf16

  k_prep2<<<5120, 256, 0, stream>>>(x, pos, mem, wqkv, wo, cbf, xp, wqt, wot);
  k_gemm_qkvs<<<1280, 256, 0, stream>>>(cbf, wqt, Qd, Kd, VTd);
  k_attn<<<1024, 128, 0, stream>>>(Qd, Kd, VTd, vec);
  k_gemm_out<<<dim3(8, 64), 256, 0, stream>>>(vec, wot, xp, y);
  k_ln<<<4096, 256, 0, stream>>>(y, gamma, beta, out);
}

// Round 15
// 170.538 us; speedup vs baseline: 1.0144x; 1.0144x over previous
//
#include <hip/hip_runtime.h>
#include <stdint.h>

// Problem constants
#define S_  1024
#define M_  1024
#define B_  4
#define D_  1024
#define H_  16
#define DH_ 64
#define T_  2048

typedef __attribute__((ext_vector_type(8))) short bf8;           // 8 x bf16 (A/B frag)
typedef __attribute__((ext_vector_type(4))) float f32x4;         // C/D frag 16x16
typedef __attribute__((ext_vector_type(16))) float f32x16;       // C/D frag 32x32
typedef __attribute__((ext_vector_type(8))) unsigned short u16x8;
typedef __attribute__((ext_vector_type(4))) unsigned short u16x4;
typedef __attribute__((ext_vector_type(4))) unsigned int u32x4;
typedef unsigned short u16;

#define MFMA(a, b, c)   __builtin_amdgcn_mfma_f32_16x16x32_bf16((a), (b), (c), 0, 0, 0)
#define MFMA32(a, b, c) __builtin_amdgcn_mfma_f32_32x32x16_bf16((a), (b), (c), 0, 0, 0)

// chunk swizzle for 64B LDS rows (cbf/wqt layout pairs with qkvs reads)
#define SIG(r) ((((r) >> 1) ^ ((r) >> 3)) & 3)
#define SCALE_Q 0.1803368801f   // 0.125 * log2(e), folded into Q at store

static __device__ __forceinline__ u16 f2bf(float f) {
  unsigned int u = __builtin_bit_cast(unsigned int, f);
  u += 0x7fffu + ((u >> 16) & 1u);   // RNE
  return (u16)(u >> 16);
}

static __device__ __forceinline__ void gload16(const void* g, void* l) {
  __builtin_amdgcn_global_load_lds((const __attribute__((address_space(1))) unsigned int*)g,
                                   (__attribute__((address_space(3))) unsigned int*)l,
                                   16, 0, 0);
}

static __device__ __forceinline__ float fexp2(float x) {
  return __builtin_amdgcn_exp2f(x);
}
static __device__ __forceinline__ unsigned int cvtpk(float lo, float hi) {
  unsigned int r; asm("v_cvt_pk_bf16_f32 %0, %1, %2" : "=v"(r) : "v"(lo), "v"(hi)); return r;
}
static __device__ __forceinline__ void plswap(unsigned int& a, unsigned int& b) {
  asm volatile("s_nop 1\n\tv_permlane32_swap_b32 %0, %1" : "+v"(a), "+v"(b));
}

// ------- merged prep: bid<4096 -> c_bf16=[mem;x+pos] (SIG-swz) + xp ---------
//         bid>=4096 -> weight transpose wqkv(SIG-swz) / wo(linear)
__global__ __launch_bounds__(256) void k_prep2(const float* __restrict__ x,
    const float* __restrict__ pos, const float* __restrict__ mem,
    const float* __restrict__ wqkv, const float* __restrict__ wo,
    u16* __restrict__ cbf, float* __restrict__ xp,
    u16* __restrict__ wqt, u16* __restrict__ wot)
{
  __shared__ float tl[64][65];
  const int bid = blockIdx.x;
  const int tid = threadIdx.x;
  if (bid < 4096) {
    const int gid = bid * 256 + tid;
    const int e = gid * 8;                  // elem idx into [8192][1024]
    const int row = e >> 10, col = e & 1023;
    float4 v0, v1;
    if (e < M_ * B_ * D_) {
      v0 = *(const float4*)(mem + e);
      v1 = *(const float4*)(mem + e + 4);
    } else {
      const int i2 = e - M_ * B_ * D_;
      v0 = *(const float4*)(x + i2);
      v1 = *(const float4*)(x + i2 + 4);
      const int srow = i2 >> 12;
      const float4 p0 = *(const float4*)(pos + srow * 1024 + col);
      const float4 p1 = *(const float4*)(pos + srow * 1024 + col + 4);
      v0.x += p0.x; v0.y += p0.y; v0.z += p0.z; v0.w += p0.w;
      v1.x += p1.x; v1.y += p1.y; v1.z += p1.z; v1.w += p1.w;
      *(float4*)(xp + i2) = v0;
      *(float4*)(xp + i2 + 4) = v1;
    }
    u16x8 c;
    c[0] = f2bf(v0.x); c[1] = f2bf(v0.y); c[2] = f2bf(v0.z); c[3] = f2bf(v0.w);
    c[4] = f2bf(v1.x); c[5] = f2bf(v1.y); c[6] = f2bf(v1.z); c[7] = f2bf(v1.w);
    const int ch = col >> 3;
    const int chs = (ch & ~3) | ((ch & 3) ^ SIG(row));
    *(u16x8*)(cbf + (size_t)row * 1024 + chs * 8) = c;
    return;
  }
  // ---- weight transpose part: 1024 blocks = 16 x 64 ----
  const int wb = bid - 4096;
  const int bx = wb & 15, by = wb >> 4;
  const float* src; u16* dst; int Cc, swz, c0;
  if (by < 48) { src = wqkv; dst = wqt; Cc = 3072; swz = 1; c0 = by * 64; }
  else         { src = wo;   dst = wot; Cc = 1024; swz = 0; c0 = (by - 48) * 64; }
  const int Rr = 1024;
  const int r0 = bx * 64;
  const int lr = tid >> 4, lc = (tid & 15) * 4;
  for (int i = 0; i < 4; ++i) {
    const int rr = lr + i * 16;
    const float4 v = *(const float4*)(src + (size_t)(r0 + rr) * Cc + c0 + lc);
    tl[rr][lc] = v.x; tl[rr][lc + 1] = v.y; tl[rr][lc + 2] = v.z; tl[rr][lc + 3] = v.w;
  }
  __syncthreads();
  const int c = tid >> 2, k0 = (tid & 3) * 16;
  u16x8 a, b;
  for (int j = 0; j < 8; ++j) { a[j] = f2bf(tl[k0 + j][c]); b[j] = f2bf(tl[k0 + 8 + j][c]); }
  const int roww = c0 + c;
  int ch0 = (r0 + k0) >> 3, ch1 = ((r0 + k0) >> 3) + 1;
  if (swz) {
    const int sx = SIG(roww);
    ch0 = (ch0 & ~3) | ((ch0 & 3) ^ sx);
    ch1 = (ch1 & ~3) | ((ch1 & 3) ^ sx);
  }
  u16* dp = dst + (size_t)roww * Rr;
  *(u16x8*)(dp + ch0 * 8) = a;
  *(u16x8*)(dp + ch1 * 8) = b;
}

// ====== QKV GEMM: 128x128, 3-stage LDS, counted vmcnt (R5/R9 proven best) ===
// V-blocks: epilogue re-staged through LDS for coalesced 16B VT stores.
// Q-blocks: store Q pre-scaled by SCALE_Q (softmax scale folded in).
__global__ __launch_bounds__(256, 3) void k_gemm_qkvs(const u16* __restrict__ A,
    const u16* __restrict__ Bt, u16* __restrict__ Qd, u16* __restrict__ Kd,
    u16* __restrict__ VTd)
{
  __shared__ u16 smem[24576];                 // 48KB: 3x8KB A | 3x8KB B
  u16 (*sA)[4096] = (u16(*)[4096])smem;
  u16 (*sB)[4096] = (u16(*)[4096])(smem + 12288);
  const int tid = threadIdx.x, lane = tid & 63, wave = tid >> 6;
  const int lrow = lane & 15, lgrp = lane >> 4;
  const int wm = (wave >> 1) * 64, wn = (wave & 1) * 64;
  const int sr = lane >> 2, sk = (lane & 3) * 8;

  // 1280 live 128x128 tiles, XCD-bijective chunking (1280 = 8*160)
  const int bid = blockIdx.x;
  const int lid = (bid & 7) * 160 + (bid >> 3);
  int rowb, colb;
  if (lid < 512) { rowb = lid >> 4; colb = 8 + (lid & 15); }
  else { const int l2 = lid - 512; const int q = l2 / 24; rowb = 32 + q; colb = l2 - q * 24; }
  const int row0 = rowb * 128, col0 = colb * 128;

  f32x4 acc[4][4];
#pragma unroll
  for (int i = 0; i < 4; ++i)
#pragma unroll
    for (int j = 0; j < 4; ++j) acc[i][j] = f32x4{0.f, 0.f, 0.f, 0.f};

#define STAGE_S(bufi, kt) do { const int k0_ = (kt) * 32;                      \
    _Pragma("unroll") for (int s_ = 0; s_ < 2; ++s_) {                         \
      const int rr_ = (wave * 2 + s_) * 16 + sr;                               \
      gload16(A + (size_t)(row0 + rr_) * 1024 + k0_ + sk,                      \
              &sA[bufi][(wave * 2 + s_) * 512]);                               \
      gload16(Bt + (size_t)(col0 + rr_) * 1024 + k0_ + sk,                     \
              &sB[bufi][(wave * 2 + s_) * 512]);                               \
    } } while (0)

  // prologue: stage tiles 0 and 1 (8 loads/thread outstanding)
  STAGE_S(0, 0); STAGE_S(1, 1);

  int c0 = 0;
#pragma unroll 1
  for (int t = 0; t < 32; ++t) {
    if (t < 31) { asm volatile("s_waitcnt vmcnt(4)" ::: "memory"); }
    else        { asm volatile("s_waitcnt vmcnt(0)" ::: "memory"); }
    __builtin_amdgcn_s_barrier();
    __builtin_amdgcn_sched_barrier(0);
    const int c2 = (c0 + 2 >= 3) ? c0 - 1 : c0 + 2;
    if (t <= 29) STAGE_S(c2, t + 2);
    bf8 af[4], bfv[4];
#pragma unroll
    for (int i = 0; i < 4; ++i) {
      const int r_ = wm + i * 16 + lrow;
      af[i] = *(const bf8*)&sA[c0][r_ * 32 + ((lgrp ^ SIG(r_)) << 3)];
    }
#pragma unroll
    for (int j = 0; j < 4; ++j) {
      const int r_ = wn + j * 16 + lrow;
      bfv[j] = *(const bf8*)&sB[c0][r_ * 32 + ((lgrp ^ SIG(r_)) << 3)];
    }
    __builtin_amdgcn_s_setprio(1);
#pragma unroll
    for (int i = 0; i < 4; ++i)
#pragma unroll
      for (int j = 0; j < 4; ++j) acc[i][j] = MFMA(af[i], bfv[j], acc[i][j]);
    __builtin_amdgcn_s_setprio(0);
    c0 = (c0 == 2) ? 0 : c0 + 1;
  }

  const int which = col0 >> 10;     // block-uniform: 0=Q 1=K 2=V
  if (which == 2) {
    // ---- V epilogue via LDS re-stage: ebuf[ro 8][dh 64][tl pad 40] ----
    __syncthreads();                 // all waves done with sA/sB reads
    u16* ebuf = smem;                // 8*64*40 u16 = 40KB (fits 48KB)
#pragma unroll
    for (int i = 0; i < 4; ++i)
#pragma unroll
      for (int j = 0; j < 4; ++j)
#pragma unroll
        for (int r = 0; r < 4; ++r) {
          const int ro = r * 2 + (wn >> 6);
          const int dh = j * 16 + lrow;
          const int tl2 = (wm >> 2) + i * 4 + lgrp;
          ebuf[(ro * 64 + dh) * 40 + tl2] = f2bf(acc[i][j][r]);
        }
    __syncthreads();
    const int h0 = (col0 & 1023) >> 6;
    const int base_t = (rowb & ~1) * 32;          // 64-aligned t base
    const int off0 = (rowb & 1) * 32;             // tile offset inside 64-chunk
#pragma unroll
    for (int k = 0; k < 8; ++k) {
      const int slot = k * 256 + tid;             // 2048 slots = 512 rows x 4
      const int row = slot >> 2, l4 = slot & 3;
      const int ro = row >> 6, dh = row & 63;
      const int b = ro >> 1, hloc = ro & 1;
      const int bh = b * 16 + h0 + hloc;
      const u16x8 v = *(const u16x8*)&ebuf[row * 40 + l4 * 8];
      const int chunk = (off0 + l4 * 8) ^ ((dh & 7) << 3);
      *(u16x8*)(VTd + (size_t)(bh * 64 + dh) * T_ + base_t + chunk) = v;
    }
    return;
  }

  // epilogue (Q / K): direct stores (already line-local)
#pragma unroll
  for (int i = 0; i < 4; ++i)
#pragma unroll
    for (int j = 0; j < 4; ++j)
#pragma unroll
      for (int r = 0; r < 4; ++r) {
        const int grow = row0 + wm + i * 16 + lgrp * 4 + r;   // c-row = t*B+b
        const int gcol = col0 + wn + j * 16 + lrow;
        const int t = grow >> 2, bb2 = grow & 3;
        const int rem = gcol & 1023;
        const int bh = bb2 * 16 + (rem >> 6), dh = rem & 63;
        if (which == 0) {
          if (t >= M_)
            Qd[((size_t)bh * S_ + (t - M_)) * 64 + dh] = f2bf(acc[i][j][r] * SCALE_Q);
        } else {
          Kd[((size_t)bh * T_ + t) * 64 + (dh ^ ((t & 7) << 3))] = f2bf(acc[i][j][r]);
        }
      }
}

// ===== out-proj GEMM: 64x128 tiles, 3-stage counted vmcnt, grid 512 =========
__global__ __launch_bounds__(256) void k_gemm_out(const u16* __restrict__ A,
    const u16* __restrict__ Bt, const float* __restrict__ xp,
    float* __restrict__ y)
{
  __shared__ u16 sA[3][2048];   // [64 rows][32 k]
  __shared__ u16 sB[3][4096];   // [128 rows][32 k]
  const int tid = threadIdx.x, lane = tid & 63, wave = tid >> 6;
  const int lrow = lane & 15, lgrp = lane >> 4;
  const int wm = (wave >> 1) * 32, wn = (wave & 1) * 64;
  const int row0 = blockIdx.y * 64, col0 = blockIdx.x * 128;
  const int sr = lane >> 2, sk = (lane & 3) * 8;

  f32x4 acc[2][4];
  for (int i = 0; i < 2; ++i)
    for (int j = 0; j < 4; ++j) acc[i][j] = f32x4{0.f, 0.f, 0.f, 0.f};

#define STAGE_O(bufi, kt) do { const int k0_ = (kt) * 32;                      \
    const int rra_ = wave * 16 + sr;                                           \
    gload16(A + (size_t)(row0 + rra_) * 1024 + k0_ + sk,                       \
            &sA[bufi][wave * 512]);                                            \
    _Pragma("unroll") for (int s_ = 0; s_ < 2; ++s_) {                         \
      const int rrb_ = (wave * 2 + s_) * 16 + sr;                              \
      gload16(Bt + (size_t)(col0 + rrb_) * 1024 + k0_ + sk,                    \
              &sB[bufi][(wave * 2 + s_) * 512]);                               \
    } } while (0)

  // prologue: tiles 0,1 staged (6 loads/thread outstanding)
  STAGE_O(0, 0); STAGE_O(1, 1);

  int c0 = 0;
#pragma unroll 1
  for (int kt = 0; kt < 32; ++kt) {
    if (kt < 31) { asm volatile("s_waitcnt vmcnt(3)" ::: "memory"); }
    else         { asm volatile("s_waitcnt vmcnt(0)" ::: "memory"); }
    __builtin_amdgcn_s_barrier();
    __builtin_amdgcn_sched_barrier(0);
    const int c2 = (c0 + 2 >= 3) ? c0 - 1 : c0 + 2;
    if (kt <= 29) STAGE_O(c2, kt + 2);
    bf8 af[2], bfv[4];
    const u16* pa = &sA[c0][(wm + lrow) * 32 + lgrp * 8];
    const u16* pb = &sB[c0][(wn + lrow) * 32 + lgrp * 8];
#pragma unroll
    for (int i = 0; i < 2; ++i) af[i] = *(const bf8*)(pa + i * 512);
#pragma unroll
    for (int j = 0; j < 4; ++j) bfv[j] = *(const bf8*)(pb + j * 512);
    __builtin_amdgcn_s_setprio(1);
#pragma unroll
    for (int i = 0; i < 2; ++i)
#pragma unroll
      for (int j = 0; j < 4; ++j) acc[i][j] = MFMA(af[i], bfv[j], acc[i][j]);
    __builtin_amdgcn_s_setprio(0);
    c0 = (c0 == 2) ? 0 : c0 + 1;
  }

  for (int i = 0; i < 2; ++i)
    for (int j = 0; j < 4; ++j)
      for (int r = 0; r < 4; ++r) {
        const int grow = row0 + wm + i * 16 + lgrp * 4 + r;
        const int gcol = col0 + wn + j * 16 + lrow;
        y[(size_t)grow * 1024 + gcol] = acc[i][j][r] + xp[(size_t)grow * 1024 + gcol];
      }
}

// ---------------- flash attention, swapped-QK^T 32x32, 4-wave blocks --------
// 1D grid 512, XCD-swizzled so each XCD owns 8 whole heads (K/V L2-resident).
// Q pre-scaled by SCALE_Q (no per-tile scale multiply).
__global__ __launch_bounds__(256) void k_attn(const u16* __restrict__ Qd,
    const u16* __restrict__ Kd, const u16* __restrict__ VTd,
    u16* __restrict__ vec)
{
  __shared__ u16 Kl[2][4096];   // [64 t][64 dh], dh XOR-swizzled
  __shared__ u16 Vl[2][4096];   // [64 dh][64 t], t  XOR-swizzled
  const int tid = threadIdx.x, lane = tid & 63, wave = tid >> 6;
  const int ql = lane & 31, hi = lane >> 5;
  const int bid = blockIdx.x;
  const int sw = (bid & 7) * 64 + (bid >> 3);   // bijective, bh-chunked per XCD
  const int bh = sw >> 3, qb = sw & 7;
  const int bb = bh >> 4, hh = bh & 15;
  const int q0 = qb * 128 + wave * 32;
  const int myq = q0 + ql;
  const int klim = M_ + myq;

  bf8 qf[4];
  const u16* qrow = Qd + ((size_t)bh * S_ + myq) * 64 + hi * 8;
#pragma unroll
  for (int c = 0; c < 4; ++c) qf[c] = *(const bf8*)(qrow + c * 16);

  const u16* kb = Kd + (size_t)bh * T_ * 64;
  const u16* vb = VTd + (size_t)bh * 64 * T_;

  f32x16 o0, o1;
#pragma unroll
  for (int r = 0; r < 16; ++r) { o0[r] = 0.f; o1[r] = 0.f; }
  float m_run = 0.f, l_run = 0.f;

  const int nkt = (M_ + qb * 128 + 128) >> 6;   // 18 + 2*qb

  auto stage = [&](int buf, int kt) {
    const int t0 = kt * 64;
#pragma unroll
    for (int i = 0; i < 2; ++i) {          // K tile: 512 chunks over 256 thr
      const int ch = i * 256 + tid;
      gload16(kb + (size_t)t0 * 64 + ch * 8, &Kl[buf][ch * 8]);
    }
#pragma unroll
    for (int i = 0; i < 2; ++i) {          // VT tile
      const int ch = i * 256 + tid;
      gload16(vb + (size_t)(ch >> 3) * T_ + t0 + (ch & 7) * 8, &Vl[buf][ch * 8]);
    }
  };

  stage(0, 0);
  int cur = 0;
  for (int kt = 0; kt < nkt; ++kt) {
    if (kt + 1 < nkt) {
      stage(cur ^ 1, kt + 1);
      asm volatile("s_waitcnt vmcnt(4)" ::: "memory");  // cur's 4 loads done
    } else {
      asm volatile("s_waitcnt vmcnt(0)" ::: "memory");
    }
    __builtin_amdgcn_s_barrier();

    const u16* Kc = Kl[cur];
    const u16* Vc = Vl[cur];

    f32x16 s0, s1;
#pragma unroll
    for (int r = 0; r < 16; ++r) { s0[r] = 0.f; s1[r] = 0.f; }
    const int tr0 = ql, tr1 = 32 + ql;
    const int sw0 = (tr0 & 7) << 3;
    __builtin_amdgcn_s_setprio(1);
#pragma unroll
    for (int c = 0; c < 4; ++c) {
      const int db = c * 16 + hi * 8;
      const bf8 ka = *(const bf8*)(Kc + tr0 * 64 + (db ^ sw0));
      const bf8 kbfr = *(const bf8*)(Kc + tr1 * 64 + (db ^ sw0));
      s0 = MFMA32(ka, qf[c], s0);
      s1 = MFMA32(kbfr, qf[c], s1);
    }
    __builtin_amdgcn_s_setprio(0);

    float p0[16], p1[16];
#pragma unroll
    for (int r = 0; r < 16; ++r) { p0[r] = s0[r]; p1[r] = s1[r]; }  // scale in Q
    if (kt * 64 + 63 > M_ + q0) {
#pragma unroll
      for (int r = 0; r < 16; ++r) {
        const int kg = kt * 64 + (r & 3) + 8 * (r >> 2) + 4 * hi;
        if (kg > klim)      p0[r] = -1e30f;
        if (kg + 32 > klim) p1[r] = -1e30f;
      }
    }
    float mx = fmaxf(p0[0], p1[0]);
#pragma unroll
    for (int r = 1; r < 16; ++r) mx = fmaxf(mx, fmaxf(p0[r], p1[r]));
    mx = fmaxf(mx, __shfl_xor(mx, 32));
    if (__any(mx - m_run > 8.f)) {
      const float mnew = fmaxf(m_run, mx);
      const float al = fexp2(m_run - mnew);
      l_run *= al;
#pragma unroll
      for (int r = 0; r < 16; ++r) {
        const int qloc = (r & 3) + 8 * (r >> 2) + 4 * hi;
        const float ar = __shfl(al, (lane & 32) + qloc);
        o0[r] *= ar; o1[r] *= ar;
      }
      m_run = mnew;
    }
    float rs = 0.f;
#pragma unroll
    for (int r = 0; r < 16; ++r) {
      p0[r] = fexp2(p0[r] - m_run);
      p1[r] = fexp2(p1[r] - m_run);
      rs += p0[r] + p1[r];
    }
    rs += __shfl_xor(rs, 32);
    l_run += rs;

    bf8 paf[2][2];
    {
      unsigned int a0 = cvtpk(p0[0], p0[1]),  a1 = cvtpk(p0[2], p0[3]);
      unsigned int a2 = cvtpk(p0[4], p0[5]),  a3 = cvtpk(p0[6], p0[7]);
      unsigned int b0 = cvtpk(p0[8], p0[9]),  b1 = cvtpk(p0[10], p0[11]);
      unsigned int b2 = cvtpk(p0[12], p0[13]), b3 = cvtpk(p0[14], p0[15]);
      plswap(a0, a2); plswap(a1, a3); plswap(b0, b2); plswap(b1, b3);
      u32x4 f0 = {a0, a1, a2, a3}, f1 = {b0, b1, b2, b3};
      paf[0][0] = __builtin_bit_cast(bf8, f0);
      paf[0][1] = __builtin_bit_cast(bf8, f1);
    }
    {
      unsigned int a0 = cvtpk(p1[0], p1[1]),  a1 = cvtpk(p1[2], p1[3]);
      unsigned int a2 = cvtpk(p1[4], p1[5]),  a3 = cvtpk(p1[6], p1[7]);
      unsigned int b0 = cvtpk(p1[8], p1[9]),  b1 = cvtpk(p1[10], p1[11]);
      unsigned int b2 = cvtpk(p1[12], p1[13]), b3 = cvtpk(p1[14], p1[15]);
      plswap(a0, a2); plswap(a1, a3); plswap(b0, b2); plswap(b1, b3);
      u32x4 f0 = {a0, a1, a2, a3}, f1 = {b0, b1, b2, b3};
      paf[1][0] = __builtin_bit_cast(bf8, f0);
      paf[1][1] = __builtin_bit_cast(bf8, f1);
    }

    __builtin_amdgcn_s_setprio(1);
#pragma unroll
    for (int kc = 0; kc < 4; ++kc) {
      const int tb = kc * 16 + hi * 8;
      const bf8 pfrag = paf[kc >> 1][kc & 1];
      const int vr0 = ql, vr1 = 32 + ql;
      const bf8 vf0 = *(const bf8*)(Vc + vr0 * 64 + (tb ^ ((vr0 & 7) << 3)));
      const bf8 vf1 = *(const bf8*)(Vc + vr1 * 64 + (tb ^ ((vr1 & 7) << 3)));
      o0 = MFMA32(pfrag, vf0, o0);
      o1 = MFMA32(pfrag, vf1, o1);
    }
    __builtin_amdgcn_s_setprio(0);
    __builtin_amdgcn_s_barrier();
    cur ^= 1;
  }

  const float linv = 1.0f / l_run;
#pragma unroll
  for (int r = 0; r < 16; ++r) {
    const int qloc = (r & 3) + 8 * (r >> 2) + 4 * hi;
    const float li = __shfl(linv, (lane & 32) + qloc);
    const int srow = q0 + qloc;
    const size_t base = ((size_t)srow * B_ + bb) * 1024 + hh * 64;
    vec[base + ql]      = f2bf(o0[r] * li);
    vec[base + 32 + ql] = f2bf(o1[r] * li);
  }
}

// ---------------- LayerNorm -------------------------------------------------
__global__ __launch_bounds__(256) void k_ln(const float* __restrict__ y,
    const float* __restrict__ g, const float* __restrict__ be,
    float* __restrict__ out)
{
  const int row = blockIdx.x, tid = threadIdx.x;
  const float4 v = *(const float4*)(y + (size_t)row * 1024 + tid * 4);
  float s = v.x + v.y + v.z + v.w;
  float ss = v.x * v.x + v.y * v.y + v.z * v.z + v.w * v.w;
  for (int mk = 1; mk < 64; mk <<= 1) { s += __shfl_xor(s, mk); ss += __shfl_xor(ss, mk); }
  __shared__ float red[8];
  if ((tid & 63) == 0) { red[tid >> 6] = s; red[4 + (tid >> 6)] = ss; }
  __syncthreads();
  s = red[0] + red[1] + red[2] + red[3];
  ss = red[4] + red[5] + red[6] + red[7];
  const float mu = s * (1.0f / 1024.0f);
  const float var = ss * (1.0f / 1024.0f) - mu * mu;
  const float rstd = rsqrtf(var + 1e-5f);
  const float4 gg = *(const float4*)(g + tid * 4);
  const float4 bb = *(const float4*)(be + tid * 4);
  float4 o;
  o.x = (v.x - mu) * rstd * gg.x + bb.x;
  o.y = (v.y - mu) * rstd * gg.y + bb.y;
  o.z = (v.z - mu) * rstd * gg.z + bb.z;
  o.w = (v.w - mu) * rstd * gg.w + bb.w;
  *(float4*)(out + (size_t)row * 1024 + tid * 4) = o;
}

// ---------------------------------------------------------------------------
extern "C" void kernel_launch(void* const* d_in, const int* in_sizes, int n_in,
                              void* d_out, int out_size, void* d_ws, size_t ws_size,
                              hipStream_t stream)
{
  const float* x     = (const float*)d_in[0];
  const float* pos   = (const float*)d_in[1];
  const float* mem   = (const float*)d_in[2];
  // d_in[3] = mask: purely causal (j > i+M), computed analytically in k_attn
  const float* wqkv  = (const float*)d_in[4];
  const float* wo    = (const float*)d_in[5];
  const float* gamma = (const float*)d_in[6];
  const float* beta  = (const float*)d_in[7];
  float* out = (float*)d_out;

  if (ws_size < ((size_t)104 << 20)) return;  // need 104 MB scratch

  char* ws = (char*)d_ws;
  u16*   cbf = (u16*)(ws + 0);                      // 16MB  [8192][1024] bf16 (sig-swz)
  float* y   = (float*)(ws + 0);                    // 16MB  (reuses cbf after gemm1)
  float* xp  = (float*)(ws + ((size_t)16 << 20));   // 16MB  [4096][1024] f32
  u16*   wqt = (u16*)(ws + ((size_t)32 << 20));     // 6MB   [3072][1024] bf16 (sig-swz)
  u16*   wot = (u16*)(ws + ((size_t)38 << 20));     // 2MB   [1024][1024] bf16
  u16*   Qd  = (u16*)(ws + ((size_t)40 << 20));     // 8MB   [64][1024][64] (pre-scaled)
  u16*   Kd  = (u16*)(ws + ((size_t)48 << 20));     // 16MB  [64][2048][64] (swz)
  u16*   VTd = (u16*)(ws + ((size_t)80 << 20));     // 16MB  [64][64][2048] (swz)
  u16*   vec = (u16*)(ws + ((size_t)96 << 20));     // 8MB   [4096][1024] bf16

  k_prep2<<<5120, 256, 0, stream>>>(x, pos, mem, wqkv, wo, cbf, xp, wqt, wot);
  k_gemm_qkvs<<<1280, 256, 0, stream>>>(cbf, wqt, Qd, Kd, VTd);
  k_attn<<<512, 256, 0, stream>>>(Qd, Kd, VTd, vec);
  k_gemm_out<<<dim3(8, 64), 256, 0, stream>>>(vec, wot, xp, y);
  k_ln<<<4096, 256, 0, stream>>>(y, gamma, beta, out);
}

// Round 16
// 162.001 us; speedup vs baseline: 1.0679x; 1.0527x over previous
//
#include <hip/hip_runtime.h>
#include <stdint.h>

// Problem constants
#define S_  1024
#define M_  1024
#define B_  4
#define D_  1024
#define H_  16
#define DH_ 64
#define T_  2048

typedef __attribute__((ext_vector_type(8))) short bf8;           // 8 x bf16 (A/B frag)
typedef __attribute__((ext_vector_type(4))) float f32x4;         // C/D frag 16x16
typedef __attribute__((ext_vector_type(16))) float f32x16;       // C/D frag 32x32
typedef __attribute__((ext_vector_type(8))) unsigned short u16x8;
typedef __attribute__((ext_vector_type(4))) unsigned short u16x4;
typedef __attribute__((ext_vector_type(4))) unsigned int u32x4;
typedef unsigned short u16;

#define MFMA(a, b, c)   __builtin_amdgcn_mfma_f32_16x16x32_bf16((a), (b), (c), 0, 0, 0)
#define MFMA32(a, b, c) __builtin_amdgcn_mfma_f32_32x32x16_bf16((a), (b), (c), 0, 0, 0)

// chunk swizzle for 64B LDS rows (cbf/wqt layout pairs with qkvs reads)
#define SIG(r) ((((r) >> 1) ^ ((r) >> 3)) & 3)
#define SCALE_Q 0.1803368801f   // 0.125 * log2(e), folded into Q at store

static __device__ __forceinline__ u16 f2bf(float f) {
  unsigned int u = __builtin_bit_cast(unsigned int, f);
  u += 0x7fffu + ((u >> 16) & 1u);   // RNE
  return (u16)(u >> 16);
}

static __device__ __forceinline__ void gload16(const void* g, void* l) {
  __builtin_amdgcn_global_load_lds((const __attribute__((address_space(1))) unsigned int*)g,
                                   (__attribute__((address_space(3))) unsigned int*)l,
                                   16, 0, 0);
}

static __device__ __forceinline__ float fexp2(float x) {
  return __builtin_amdgcn_exp2f(x);
}
static __device__ __forceinline__ unsigned int cvtpk(float lo, float hi) {
  unsigned int r; asm("v_cvt_pk_bf16_f32 %0, %1, %2" : "=v"(r) : "v"(lo), "v"(hi)); return r;
}
static __device__ __forceinline__ void plswap(unsigned int& a, unsigned int& b) {
  asm volatile("s_nop 1\n\tv_permlane32_swap_b32 %0, %1" : "+v"(a), "+v"(b));
}

// ------- merged prep: bid<4096 -> c_bf16=[mem;x+pos] (SIG-swz) + xp ---------
//         bid>=4096 -> weight transpose wqkv(SIG-swz) / wo(linear)
__global__ __launch_bounds__(256) void k_prep2(const float* __restrict__ x,
    const float* __restrict__ pos, const float* __restrict__ mem,
    const float* __restrict__ wqkv, const float* __restrict__ wo,
    u16* __restrict__ cbf, float* __restrict__ xp,
    u16* __restrict__ wqt, u16* __restrict__ wot)
{
  __shared__ float tl[64][65];
  const int bid = blockIdx.x;
  const int tid = threadIdx.x;
  if (bid < 4096) {
    const int gid = bid * 256 + tid;
    const int e = gid * 8;                  // elem idx into [8192][1024]
    const int row = e >> 10, col = e & 1023;
    float4 v0, v1;
    if (e < M_ * B_ * D_) {
      v0 = *(const float4*)(mem + e);
      v1 = *(const float4*)(mem + e + 4);
    } else {
      const int i2 = e - M_ * B_ * D_;
      v0 = *(const float4*)(x + i2);
      v1 = *(const float4*)(x + i2 + 4);
      const int srow = i2 >> 12;
      const float4 p0 = *(const float4*)(pos + srow * 1024 + col);
      const float4 p1 = *(const float4*)(pos + srow * 1024 + col + 4);
      v0.x += p0.x; v0.y += p0.y; v0.z += p0.z; v0.w += p0.w;
      v1.x += p1.x; v1.y += p1.y; v1.z += p1.z; v1.w += p1.w;
      *(float4*)(xp + i2) = v0;
      *(float4*)(xp + i2 + 4) = v1;
    }
    u16x8 c;
    c[0] = f2bf(v0.x); c[1] = f2bf(v0.y); c[2] = f2bf(v0.z); c[3] = f2bf(v0.w);
    c[4] = f2bf(v1.x); c[5] = f2bf(v1.y); c[6] = f2bf(v1.z); c[7] = f2bf(v1.w);
    const int ch = col >> 3;
    const int chs = (ch & ~3) | ((ch & 3) ^ SIG(row));
    *(u16x8*)(cbf + (size_t)row * 1024 + chs * 8) = c;
    return;
  }
  // ---- weight transpose part: 1024 blocks = 16 x 64 ----
  const int wb = bid - 4096;
  const int bx = wb & 15, by = wb >> 4;
  const float* src; u16* dst; int Cc, swz, c0;
  if (by < 48) { src = wqkv; dst = wqt; Cc = 3072; swz = 1; c0 = by * 64; }
  else         { src = wo;   dst = wot; Cc = 1024; swz = 0; c0 = (by - 48) * 64; }
  const int Rr = 1024;
  const int r0 = bx * 64;
  const int lr = tid >> 4, lc = (tid & 15) * 4;
  for (int i = 0; i < 4; ++i) {
    const int rr = lr + i * 16;
    const float4 v = *(const float4*)(src + (size_t)(r0 + rr) * Cc + c0 + lc);
    tl[rr][lc] = v.x; tl[rr][lc + 1] = v.y; tl[rr][lc + 2] = v.z; tl[rr][lc + 3] = v.w;
  }
  __syncthreads();
  const int c = tid >> 2, k0 = (tid & 3) * 16;
  u16x8 a, b;
  for (int j = 0; j < 8; ++j) { a[j] = f2bf(tl[k0 + j][c]); b[j] = f2bf(tl[k0 + 8 + j][c]); }
  const int roww = c0 + c;
  int ch0 = (r0 + k0) >> 3, ch1 = ((r0 + k0) >> 3) + 1;
  if (swz) {
    const int sx = SIG(roww);
    ch0 = (ch0 & ~3) | ((ch0 & 3) ^ sx);
    ch1 = (ch1 & ~3) | ((ch1 & 3) ^ sx);
  }
  u16* dp = dst + (size_t)roww * Rr;
  *(u16x8*)(dp + ch0 * 8) = a;
  *(u16x8*)(dp + ch1 * 8) = b;
}

// ====== QKV GEMM: 128x128, 3-stage LDS, counted vmcnt (R5/R9 proven best) ===
// V-blocks: epilogue re-staged through LDS for coalesced 16B VT stores.
// Q-blocks: store Q pre-scaled by SCALE_Q (softmax scale folded in).
__global__ __launch_bounds__(256, 3) void k_gemm_qkvs(const u16* __restrict__ A,
    const u16* __restrict__ Bt, u16* __restrict__ Qd, u16* __restrict__ Kd,
    u16* __restrict__ VTd)
{
  __shared__ u16 smem[24576];                 // 48KB: 3x8KB A | 3x8KB B
  u16 (*sA)[4096] = (u16(*)[4096])smem;
  u16 (*sB)[4096] = (u16(*)[4096])(smem + 12288);
  const int tid = threadIdx.x, lane = tid & 63, wave = tid >> 6;
  const int lrow = lane & 15, lgrp = lane >> 4;
  const int wm = (wave >> 1) * 64, wn = (wave & 1) * 64;
  const int sr = lane >> 2, sk = (lane & 3) * 8;

  // 1280 live 128x128 tiles, XCD-bijective chunking (1280 = 8*160)
  const int bid = blockIdx.x;
  const int lid = (bid & 7) * 160 + (bid >> 3);
  int rowb, colb;
  if (lid < 512) { rowb = lid >> 4; colb = 8 + (lid & 15); }
  else { const int l2 = lid - 512; const int q = l2 / 24; rowb = 32 + q; colb = l2 - q * 24; }
  const int row0 = rowb * 128, col0 = colb * 128;

  f32x4 acc[4][4];
#pragma unroll
  for (int i = 0; i < 4; ++i)
#pragma unroll
    for (int j = 0; j < 4; ++j) acc[i][j] = f32x4{0.f, 0.f, 0.f, 0.f};

#define STAGE_S(bufi, kt) do { const int k0_ = (kt) * 32;                      \
    _Pragma("unroll") for (int s_ = 0; s_ < 2; ++s_) {                         \
      const int rr_ = (wave * 2 + s_) * 16 + sr;                               \
      gload16(A + (size_t)(row0 + rr_) * 1024 + k0_ + sk,                      \
              &sA[bufi][(wave * 2 + s_) * 512]);                               \
      gload16(Bt + (size_t)(col0 + rr_) * 1024 + k0_ + sk,                     \
              &sB[bufi][(wave * 2 + s_) * 512]);                               \
    } } while (0)

  // prologue: stage tiles 0 and 1 (8 loads/thread outstanding)
  STAGE_S(0, 0); STAGE_S(1, 1);

  int c0 = 0;
#pragma unroll 1
  for (int t = 0; t < 32; ++t) {
    if (t < 31) { asm volatile("s_waitcnt vmcnt(4)" ::: "memory"); }
    else        { asm volatile("s_waitcnt vmcnt(0)" ::: "memory"); }
    __builtin_amdgcn_s_barrier();
    __builtin_amdgcn_sched_barrier(0);
    const int c2 = (c0 + 2 >= 3) ? c0 - 1 : c0 + 2;
    if (t <= 29) STAGE_S(c2, t + 2);
    bf8 af[4], bfv[4];
#pragma unroll
    for (int i = 0; i < 4; ++i) {
      const int r_ = wm + i * 16 + lrow;
      af[i] = *(const bf8*)&sA[c0][r_ * 32 + ((lgrp ^ SIG(r_)) << 3)];
    }
#pragma unroll
    for (int j = 0; j < 4; ++j) {
      const int r_ = wn + j * 16 + lrow;
      bfv[j] = *(const bf8*)&sB[c0][r_ * 32 + ((lgrp ^ SIG(r_)) << 3)];
    }
    __builtin_amdgcn_s_setprio(1);
#pragma unroll
    for (int i = 0; i < 4; ++i)
#pragma unroll
      for (int j = 0; j < 4; ++j) acc[i][j] = MFMA(af[i], bfv[j], acc[i][j]);
    __builtin_amdgcn_s_setprio(0);
    c0 = (c0 == 2) ? 0 : c0 + 1;
  }

  const int which = col0 >> 10;     // block-uniform: 0=Q 1=K 2=V
  if (which == 2) {
    // ---- V epilogue via LDS re-stage: ebuf[ro 8][dh 64][tl pad 40] ----
    __syncthreads();                 // all waves done with sA/sB reads
    u16* ebuf = smem;                // 8*64*40 u16 = 40KB (fits 48KB)
#pragma unroll
    for (int i = 0; i < 4; ++i)
#pragma unroll
      for (int j = 0; j < 4; ++j)
#pragma unroll
        for (int r = 0; r < 4; ++r) {
          const int ro = r * 2 + (wn >> 6);
          const int dh = j * 16 + lrow;
          const int tl2 = (wm >> 2) + i * 4 + lgrp;
          ebuf[(ro * 64 + dh) * 40 + tl2] = f2bf(acc[i][j][r]);
        }
    __syncthreads();
    const int h0 = (col0 & 1023) >> 6;
    const int base_t = (rowb & ~1) * 32;          // 64-aligned t base
    const int off0 = (rowb & 1) * 32;             // tile offset inside 64-chunk
#pragma unroll
    for (int k = 0; k < 8; ++k) {
      const int slot = k * 256 + tid;             // 2048 slots = 512 rows x 4
      const int row = slot >> 2, l4 = slot & 3;
      const int ro = row >> 6, dh = row & 63;
      const int b = ro >> 1, hloc = ro & 1;
      const int bh = b * 16 + h0 + hloc;
      const u16x8 v = *(const u16x8*)&ebuf[row * 40 + l4 * 8];
      const int chunk = (off0 + l4 * 8) ^ ((dh & 7) << 3);
      *(u16x8*)(VTd + (size_t)(bh * 64 + dh) * T_ + base_t + chunk) = v;
    }
    return;
  }

  // epilogue (Q / K): direct stores (already line-local)
#pragma unroll
  for (int i = 0; i < 4; ++i)
#pragma unroll
    for (int j = 0; j < 4; ++j)
#pragma unroll
      for (int r = 0; r < 4; ++r) {
        const int grow = row0 + wm + i * 16 + lgrp * 4 + r;   // c-row = t*B+b
        const int gcol = col0 + wn + j * 16 + lrow;
        const int t = grow >> 2, bb2 = grow & 3;
        const int rem = gcol & 1023;
        const int bh = bb2 * 16 + (rem >> 6), dh = rem & 63;
        if (which == 0) {
          if (t >= M_)
            Qd[((size_t)bh * S_ + (t - M_)) * 64 + dh] = f2bf(acc[i][j][r] * SCALE_Q);
        } else {
          Kd[((size_t)bh * T_ + t) * 64 + (dh ^ ((t & 7) << 3))] = f2bf(acc[i][j][r]);
        }
      }
}

// ===== out-proj GEMM: 64x128 tiles, 3-stage counted vmcnt, grid 512 =========
__global__ __launch_bounds__(256) void k_gemm_out(const u16* __restrict__ A,
    const u16* __restrict__ Bt, const float* __restrict__ xp,
    float* __restrict__ y)
{
  __shared__ u16 sA[3][2048];   // [64 rows][32 k]
  __shared__ u16 sB[3][4096];   // [128 rows][32 k]
  const int tid = threadIdx.x, lane = tid & 63, wave = tid >> 6;
  const int lrow = lane & 15, lgrp = lane >> 4;
  const int wm = (wave >> 1) * 32, wn = (wave & 1) * 64;
  const int row0 = blockIdx.y * 64, col0 = blockIdx.x * 128;
  const int sr = lane >> 2, sk = (lane & 3) * 8;

  f32x4 acc[2][4];
  for (int i = 0; i < 2; ++i)
    for (int j = 0; j < 4; ++j) acc[i][j] = f32x4{0.f, 0.f, 0.f, 0.f};

#define STAGE_O(bufi, kt) do { const int k0_ = (kt) * 32;                      \
    const int rra_ = wave * 16 + sr;                                           \
    gload16(A + (size_t)(row0 + rra_) * 1024 + k0_ + sk,                       \
            &sA[bufi][wave * 512]);                                            \
    _Pragma("unroll") for (int s_ = 0; s_ < 2; ++s_) {                         \
      const int rrb_ = (wave * 2 + s_) * 16 + sr;                              \
      gload16(Bt + (size_t)(col0 + rrb_) * 1024 + k0_ + sk,                    \
              &sB[bufi][(wave * 2 + s_) * 512]);                               \
    } } while (0)

  // prologue: tiles 0,1 staged (6 loads/thread outstanding)
  STAGE_O(0, 0); STAGE_O(1, 1);

  int c0 = 0;
#pragma unroll 1
  for (int kt = 0; kt < 32; ++kt) {
    if (kt < 31) { asm volatile("s_waitcnt vmcnt(3)" ::: "memory"); }
    else         { asm volatile("s_waitcnt vmcnt(0)" ::: "memory"); }
    __builtin_amdgcn_s_barrier();
    __builtin_amdgcn_sched_barrier(0);
    const int c2 = (c0 + 2 >= 3) ? c0 - 1 : c0 + 2;
    if (kt <= 29) STAGE_O(c2, kt + 2);
    bf8 af[2], bfv[4];
    const u16* pa = &sA[c0][(wm + lrow) * 32 + lgrp * 8];
    const u16* pb = &sB[c0][(wn + lrow) * 32 + lgrp * 8];
#pragma unroll
    for (int i = 0; i < 2; ++i) af[i] = *(const bf8*)(pa + i * 512);
#pragma unroll
    for (int j = 0; j < 4; ++j) bfv[j] = *(const bf8*)(pb + j * 512);
    __builtin_amdgcn_s_setprio(1);
#pragma unroll
    for (int i = 0; i < 2; ++i)
#pragma unroll
      for (int j = 0; j < 4; ++j) acc[i][j] = MFMA(af[i], bfv[j], acc[i][j]);
    __builtin_amdgcn_s_setprio(0);
    c0 = (c0 == 2) ? 0 : c0 + 1;
  }

  for (int i = 0; i < 2; ++i)
    for (int j = 0; j < 4; ++j)
      for (int r = 0; r < 4; ++r) {
        const int grow = row0 + wm + i * 16 + lgrp * 4 + r;
        const int gcol = col0 + wn + j * 16 + lrow;
        y[(size_t)grow * 1024 + gcol] = acc[i][j][r] + xp[(size_t)grow * 1024 + gcol];
      }
}

// ---------------- flash attention, swapped-QK^T 32x32, 4-wave blocks --------
// 1D grid 512. Work-balanced XCD mapping: co-resident pair (bid, bid+256)
// gets complementary qb (sum=7) so per-CU work is ~constant (50 tiles);
// each XCD still owns 8 whole heads (K/V L2-resident).
__global__ __launch_bounds__(256) void k_attn(const u16* __restrict__ Qd,
    const u16* __restrict__ Kd, const u16* __restrict__ VTd,
    u16* __restrict__ vec)
{
  __shared__ u16 Kl[2][4096];   // [64 t][64 dh], dh XOR-swizzled
  __shared__ u16 Vl[2][4096];   // [64 dh][64 t], t  XOR-swizzled
  const int tid = threadIdx.x, lane = tid & 63, wave = tid >> 6;
  const int ql = lane & 31, hi = lane >> 5;
  const int bid = blockIdx.x;
  const int hsel = bid >> 8, p = bid & 255;
  const int idx = p >> 3;
  const int bh = (p & 7) * 8 + (idx & 7);
  const int qb0 = idx >> 3;
  const int qb = hsel ? 7 - qb0 : qb0;
  const int bb = bh >> 4, hh = bh & 15;
  const int q0 = qb * 128 + wave * 32;
  const int myq = q0 + ql;
  const int klim = M_ + myq;

  bf8 qf[4];
  const u16* qrow = Qd + ((size_t)bh * S_ + myq) * 64 + hi * 8;
#pragma unroll
  for (int c = 0; c < 4; ++c) qf[c] = *(const bf8*)(qrow + c * 16);

  const u16* kb = Kd + (size_t)bh * T_ * 64;
  const u16* vb = VTd + (size_t)bh * 64 * T_;

  f32x16 o0, o1;
#pragma unroll
  for (int r = 0; r < 16; ++r) { o0[r] = 0.f; o1[r] = 0.f; }
  float m_run = 0.f, l_run = 0.f;

  const int nkt = (M_ + qb * 128 + 128) >> 6;   // 18 + 2*qb

  auto stage = [&](int buf, int kt) {
    const int t0 = kt * 64;
#pragma unroll
    for (int i = 0; i < 2; ++i) {          // K tile: 512 chunks over 256 thr
      const int ch = i * 256 + tid;
      gload16(kb + (size_t)t0 * 64 + ch * 8, &Kl[buf][ch * 8]);
    }
#pragma unroll
    for (int i = 0; i < 2; ++i) {          // VT tile
      const int ch = i * 256 + tid;
      gload16(vb + (size_t)(ch >> 3) * T_ + t0 + (ch & 7) * 8, &Vl[buf][ch * 8]);
    }
  };

  stage(0, 0);
  int cur = 0;
  for (int kt = 0; kt < nkt; ++kt) {
    if (kt + 1 < nkt) {
      stage(cur ^ 1, kt + 1);
      asm volatile("s_waitcnt vmcnt(4)" ::: "memory");  // cur's 4 loads done
    } else {
      asm volatile("s_waitcnt vmcnt(0)" ::: "memory");
    }
    __builtin_amdgcn_s_barrier();

    const u16* Kc = Kl[cur];
    const u16* Vc = Vl[cur];

    f32x16 s0, s1;
#pragma unroll
    for (int r = 0; r < 16; ++r) { s0[r] = 0.f; s1[r] = 0.f; }
    const int tr0 = ql, tr1 = 32 + ql;
    const int sw0 = (tr0 & 7) << 3;
    __builtin_amdgcn_s_setprio(1);
#pragma unroll
    for (int c = 0; c < 4; ++c) {
      const int db = c * 16 + hi * 8;
      const bf8 ka = *(const bf8*)(Kc + tr0 * 64 + (db ^ sw0));
      const bf8 kbfr = *(const bf8*)(Kc + tr1 * 64 + (db ^ sw0));
      s0 = MFMA32(ka, qf[c], s0);
      s1 = MFMA32(kbfr, qf[c], s1);
    }
    __builtin_amdgcn_s_setprio(0);

    float p0[16], p1[16];
#pragma unroll
    for (int r = 0; r < 16; ++r) { p0[r] = s0[r]; p1[r] = s1[r]; }  // scale in Q
    if (kt * 64 + 63 > M_ + q0) {
#pragma unroll
      for (int r = 0; r < 16; ++r) {
        const int kg = kt * 64 + (r & 3) + 8 * (r >> 2) + 4 * hi;
        if (kg > klim)      p0[r] = -1e30f;
        if (kg + 32 > klim) p1[r] = -1e30f;
      }
    }
    float mx = fmaxf(p0[0], p1[0]);
#pragma unroll
    for (int r = 1; r < 16; ++r) mx = fmaxf(mx, fmaxf(p0[r], p1[r]));
    mx = fmaxf(mx, __shfl_xor(mx, 32));
    if (__any(mx - m_run > 8.f)) {
      const float mnew = fmaxf(m_run, mx);
      const float al = fexp2(m_run - mnew);
      l_run *= al;
#pragma unroll
      for (int r = 0; r < 16; ++r) {
        const int qloc = (r & 3) + 8 * (r >> 2) + 4 * hi;
        const float ar = __shfl(al, (lane & 32) + qloc);
        o0[r] *= ar; o1[r] *= ar;
      }
      m_run = mnew;
    }
    float rs = 0.f;
#pragma unroll
    for (int r = 0; r < 16; ++r) {
      p0[r] = fexp2(p0[r] - m_run);
      p1[r] = fexp2(p1[r] - m_run);
      rs += p0[r] + p1[r];
    }
    rs += __shfl_xor(rs, 32);
    l_run += rs;

    bf8 paf[2][2];
    {
      unsigned int a0 = cvtpk(p0[0], p0[1]),  a1 = cvtpk(p0[2], p0[3]);
      unsigned int a2 = cvtpk(p0[4], p0[5]),  a3 = cvtpk(p0[6], p0[7]);
      unsigned int b0 = cvtpk(p0[8], p0[9]),  b1 = cvtpk(p0[10], p0[11]);
      unsigned int b2 = cvtpk(p0[12], p0[13]), b3 = cvtpk(p0[14], p0[15]);
      plswap(a0, a2); plswap(a1, a3); plswap(b0, b2); plswap(b1, b3);
      u32x4 f0 = {a0, a1, a2, a3}, f1 = {b0, b1, b2, b3};
      paf[0][0] = __builtin_bit_cast(bf8, f0);
      paf[0][1] = __builtin_bit_cast(bf8, f1);
    }
    {
      unsigned int a0 = cvtpk(p1[0], p1[1]),  a1 = cvtpk(p1[2], p1[3]);
      unsigned int a2 = cvtpk(p1[4], p1[5]),  a3 = cvtpk(p1[6], p1[7]);
      unsigned int b0 = cvtpk(p1[8], p1[9]),  b1 = cvtpk(p1[10], p1[11]);
      unsigned int b2 = cvtpk(p1[12], p1[13]), b3 = cvtpk(p1[14], p1[15]);
      plswap(a0, a2); plswap(a1, a3); plswap(b0, b2); plswap(b1, b3);
      u32x4 f0 = {a0, a1, a2, a3}, f1 = {b0, b1, b2, b3};
      paf[1][0] = __builtin_bit_cast(bf8, f0);
      paf[1][1] = __builtin_bit_cast(bf8, f1);
    }

    __builtin_amdgcn_s_setprio(1);
#pragma unroll
    for (int kc = 0; kc < 4; ++kc) {
      const int tb = kc * 16 + hi * 8;
      const bf8 pfrag = paf[kc >> 1][kc & 1];
      const int vr0 = ql, vr1 = 32 + ql;
      const bf8 vf0 = *(const bf8*)(Vc + vr0 * 64 + (tb ^ ((vr0 & 7) << 3)));
      const bf8 vf1 = *(const bf8*)(Vc + vr1 * 64 + (tb ^ ((vr1 & 7) << 3)));
      o0 = MFMA32(pfrag, vf0, o0);
      o1 = MFMA32(pfrag, vf1, o1);
    }
    __builtin_amdgcn_s_setprio(0);
    __builtin_amdgcn_s_barrier();
    cur ^= 1;
  }

  const float linv = 1.0f / l_run;
#pragma unroll
  for (int r = 0; r < 16; ++r) {
    const int qloc = (r & 3) + 8 * (r >> 2) + 4 * hi;
    const float li = __shfl(linv, (lane & 32) + qloc);
    const int srow = q0 + qloc;
    const size_t base = ((size_t)srow * B_ + bb) * 1024 + hh * 64;
    vec[base + ql]      = f2bf(o0[r] * li);
    vec[base + 32 + ql] = f2bf(o1[r] * li);
  }
}

// ---------------- LayerNorm -------------------------------------------------
__global__ __launch_bounds__(256) void k_ln(const float* __restrict__ y,
    const float* __restrict__ g, const float* __restrict__ be,
    float* __restrict__ out)
{
  const int row = blockIdx.x, tid = threadIdx.x;
  const float4 v = *(const float4*)(y + (size_t)row * 1024 + tid * 4);
  float s = v.x + v.y + v.z + v.w;
  float ss = v.x * v.x + v.y * v.y + v.z * v.z + v.w * v.w;
  for (int mk = 1; mk < 64; mk <<= 1) { s += __shfl_xor(s, mk); ss += __shfl_xor(ss, mk); }
  __shared__ float red[8];
  if ((tid & 63) == 0) { red[tid >> 6] = s; red[4 + (tid >> 6)] = ss; }
  __syncthreads();
  s = red[0] + red[1] + red[2] + red[3];
  ss = red[4] + red[5] + red[6] + red[7];
  const float mu = s * (1.0f / 1024.0f);
  const float var = ss * (1.0f / 1024.0f) - mu * mu;
  const float rstd = rsqrtf(var + 1e-5f);
  const float4 gg = *(const float4*)(g + tid * 4);
  const float4 bb = *(const float4*)(be + tid * 4);
  float4 o;
  o.x = (v.x - mu) * rstd * gg.x + bb.x;
  o.y = (v.y - mu) * rstd * gg.y + bb.y;
  o.z = (v.z - mu) * rstd * gg.z + bb.z;
  o.w = (v.w - mu) * rstd * gg.w + bb.w;
  *(float4*)(out + (size_t)row * 1024 + tid * 4) = o;
}

// ---------------------------------------------------------------------------
extern "C" void kernel_launch(void* const* d_in, const int* in_sizes, int n_in,
                              void* d_out, int out_size, void* d_ws, size_t ws_size,
                              hipStream_t stream)
{
  const float* x     = (const float*)d_in[0];
  const float* pos   = (const float*)d_in[1];
  const float* mem   = (const float*)d_in[2];
  // d_in[3] = mask: purely causal (j > i+M), computed analytically in k_attn
  const float* wqkv  = (const float*)d_in[4];
  const float* wo    = (const float*)d_in[5];
  const float* gamma = (const float*)d_in[6];
  const float* beta  = (const float*)d_in[7];
  float* out = (float*)d_out;

  if (ws_size < ((size_t)104 << 20)) return;  // need 104 MB scratch

  char* ws = (char*)d_ws;
  u16*   cbf = (u16*)(ws + 0);                      // 16MB  [8192][1024] bf16 (sig-swz)
  float* y   = (float*)(ws + 0);                    // 16MB  (reuses cbf after gemm1)
  float* xp  = (float*)(ws + ((size_t)16 << 20));   // 16MB  [4096][1024] f32
  u16*   wqt = (u16*)(ws + ((size_t)32 << 20));     // 6MB   [3072][1024] bf16 (sig-swz)
  u16*   wot = (u16*)(ws + ((size_t)38 << 20));     // 2MB   [1024][1024] bf16
  u16*   Qd  = (u16*)(ws + ((size_t)40 << 20));     // 8MB   [64][1024][64] (pre-scaled)
  u16*   Kd  = (u16*)(ws + ((size_t)48 << 20));     // 16MB  [64][2048][64] (swz)
  u16*   VTd = (u16*)(ws + ((size_t)80 << 20));     // 16MB  [64][64][2048] (swz)
  u16*   vec = (u16*)(ws + ((size_t)96 << 20));     // 8MB   [4096][1024] bf16

  k_prep2<<<5120, 256, 0, stream>>>(x, pos, mem, wqkv, wo, cbf, xp, wqt, wot);
  k_gemm_qkvs<<<1280, 256, 0, stream>>>(cbf, wqt, Qd, Kd, VTd);
  k_attn<<<512, 256, 0, stream>>>(Qd, Kd, VTd, vec);
  k_gemm_out<<<dim3(8, 64), 256, 0, stream>>>(vec, wot, xp, y);
  k_ln<<<4096, 256, 0, stream>>>(y, gamma, beta, out);
}